// Round 10
// baseline (216.584 us; speedup 1.0000x reference)
//
#include <hip/hip_runtime.h>
#include <stdint.h>

#define NB 256
#define NL 128
#define ND1 512
#define ND2 512
#define NE 64

#define BI 128              // i-tile width per block
#define BK 64               // k-tile depth (fp32 in LDS)
#define NKT (ND2 / BK)      // 8 k-tiles
// LDS: single buffer, A tile 128x64 fp32 (32KB) + B tile 128x64 fp32 (32KB).
// Layout: 16B chunks, 16 chunks/row, LINEAR slots (global_load_lds requires
// linear dest). Chunk cr of row r is stored at slot r*16 + (cr ^ ((r>>1)&7))
// -- realized by permuting the per-lane GLOBAL source address (rule #21:
// inverse-swizzle source + swizzled read). Reads then hit the 8-lanes-per-
// bank-group floor (conflict-free in the m134 sense).

typedef float float4_t __attribute__((ext_vector_type(4)));
typedef __bf16 bf16x8_t __attribute__((ext_vector_type(8)));

#define GLOAD16(gp, lp) __builtin_amdgcn_global_load_lds( \
    (const __attribute__((address_space(1))) void*)(gp),  \
    (__attribute__((address_space(3))) void*)(lp), 16, 0, 0)

// fp32x8 (two float4 chunks) -> bf16x8 via hardware v_cvt_pk_bf16_f32 (RNE)
__device__ __forceinline__ bf16x8_t cvt8f(float4_t lo, float4_t hi) {
    bf16x8_t r;
    r[0] = (__bf16)lo.x; r[1] = (__bf16)lo.y; r[2] = (__bf16)lo.z; r[3] = (__bf16)lo.w;
    r[4] = (__bf16)hi.x; r[5] = (__bf16)hi.y; r[6] = (__bf16)hi.z; r[7] = (__bf16)hi.w;
    return r;
}

// Pre-pass: zero output + counting-sort batches by expert id -> perm.
__global__ void pre_kernel(const int* __restrict__ pidx, int* __restrict__ perm,
                           float* __restrict__ out, int zero_n, int do_sort)
{
    const int g = blockIdx.x, t = threadIdx.x;
    const int idx = g * 256 + t;
    if (idx < zero_n) out[idx] = 0.f;
    if (do_sort && g == 0) {
        __shared__ int cnt[NE];
        __shared__ int base[NE];
        if (t < NE) cnt[t] = 0;
        __syncthreads();
        const int e = pidx[t];
        const int r = atomicAdd(&cnt[e], 1);
        __syncthreads();
        if (t == 0) {
            int s = 0;
            for (int i = 0; i < NE; ++i) { base[i] = s; s += cnt[i]; }
        }
        __syncthreads();
        perm[base[e] + r] = t;
    }
}

// Z = T2 (128 x 512) x W^T; out[b,l] = sum_i Z[l,i] * t1[b,l,i]
//
// m97-family staging: global_load_lds DMA (8 instrs/wave/tile), single
// 64KB LDS buffer, 2-barrier loop:
//   compute(kt) -> lgkm(0)+barrier -> DMA(kt+1) -> vmcnt(0)+barrier
// No VGPR round-trip, no staging f2bf, no ds_writes. fp32->bf16 happens
// at fragment-read time (cvt_pk). 512 thr / 8 waves = 4(wv) x 2(ih),
// acc[2][4] = 32 AGPR. 2 blocks/CU; grid 1024 = 2 rounds.
// Placement: expert-sorted perm, XCD x owns slots x*32..x*32+31, it=0..3
// of each b co-resident on one XCD (t2+weight L2 reuse) -- proven R4/R5.
template <bool USE_PERM>
__global__ __launch_bounds__(512, 2) void pdot_kernel(
    const float* __restrict__ t1, const float* __restrict__ t2,
    const int* __restrict__ pidx, const float* __restrict__ wgt,
    const int* __restrict__ perm, float* __restrict__ out)
{
    __shared__ float sm[2 * NL * BK];   // [ A: 8192 floats | B: 8192 floats ]

    const int g  = blockIdx.x;
    const int x  = g & 7;                 // XCD
    const int s  = g >> 3;                // per-XCD sequence 0..127
    const int slot = x * 32 + (s >> 2);   // expert-sorted batch slot
    const int b  = USE_PERM ? perm[slot] : slot;
    const int it = s & 3;
    const int i0 = it * BI;

    const int t  = threadIdx.x;
    const int w  = t >> 6;         // wave 0..7
    const int wv = w & 3;          // l-group: rows wv*32..wv*32+31
    const int ih = w >> 2;         // i-half: cols ih*64..ih*64+63 of the tile
    const int ln = t & 63;
    const int nh = ln & 15;
    const int qd = ln >> 4;

    const int e = pidx[b];
    const float* aPtr = t2  + (size_t)b * (NL * ND2);
    const float* bPtr = wgt + (size_t)e * (ND1 * ND2) + (size_t)i0 * ND2;
    const float* t1p  = t1  + (size_t)b * (NL * ND1) + i0 + ih * 64;

    float4_t acc[2][4];
    #pragma unroll
    for (int i = 0; i < 2; ++i)
        #pragma unroll
        for (int j = 0; j < 4; ++j) {
            float4_t z = {0.f, 0.f, 0.f, 0.f};
            acc[i][j] = z;
        }

    // ---- staging descriptors: wave w, instr q covers slots w*256+q*64+ln ----
    // slot -> row r = slot>>4, chunk-in-row c = slot&15; stored data chunk
    // cr = c ^ ((r>>1)&7). Per-lane global float offset = r*ND2 + cr*4.
    // LDS dest (wave-uniform!) = slot_base*16 bytes.
    const float* aSrc[4];
    const float* bSrc[4];
    unsigned dstByte[4];
    #pragma unroll
    for (int q = 0; q < 4; ++q) {
        const int sl = w * 256 + q * 64 + ln;
        const int r  = sl >> 4;
        const int c  = sl & 15;
        const int m  = (r >> 1) & 7;
        const int cr = c ^ m;                   // m<8: XOR affects low 3 bits only
        const int off = r * ND2 + cr * 4;
        aSrc[q] = aPtr + off;
        bSrc[q] = bPtr + off;
        dstByte[q] = (unsigned)((w * 256 + q * 64) * 16);
    }
    char* const smB = (char*)&sm[0];

    // ---- fragment read addresses (loop-invariant byte offsets) ----
    // cs = (qd*2) ^ ((nh>>1)&7); ks adds +8 chunks (ks*8 has no low-3 bits).
    const int m  = (nh >> 1) & 7;
    const int cs = ((qd * 2) ^ m) << 4;         // byte offset of lo chunk in row
    const int raA = wv * 32 + nh;               // A rows raA, raA+16
    const int aRow0 = raA * 256;                // 256 B per row
    const int bRowBase = (ih * 64 + nh) * 256;  // + ns*16*256

    // ---- prologue: DMA tile 0, publish ----
    #pragma unroll
    for (int q = 0; q < 4; ++q) {
        GLOAD16(aSrc[q], smB + dstByte[q]);
        GLOAD16(bSrc[q], smB + 32768 + dstByte[q]);
    }
    __builtin_amdgcn_sched_barrier(0);
    asm volatile("s_waitcnt vmcnt(0)" ::: "memory");
    __builtin_amdgcn_sched_barrier(0);
    __builtin_amdgcn_s_barrier();
    __builtin_amdgcn_sched_barrier(0);

    for (int kt = 0; kt < NKT; ++kt) {
        // ---- compute tile kt from LDS ----
        #pragma unroll
        for (int ks = 0; ks < 2; ++ks) {
            const int cb = cs + ks * 128;       // + ks*8 chunks * 16 B
            float4_t lo0 = *(const float4_t*)(smB + (aRow0        + cb));
            float4_t hi0 = *(const float4_t*)(smB + ((aRow0       + cb) ^ 16));
            float4_t lo1 = *(const float4_t*)(smB + (aRow0 + 4096 + cb));
            float4_t hi1 = *(const float4_t*)(smB + ((aRow0 + 4096 + cb) ^ 16));
            bf16x8_t af0 = cvt8f(lo0, hi0);
            bf16x8_t af1 = cvt8f(lo1, hi1);
            #pragma unroll
            for (int ns = 0; ns < 4; ++ns) {
                const int ba = 32768 + bRowBase + ns * 4096 + cb;
                float4_t bl = *(const float4_t*)(smB + ba);
                float4_t bh = *(const float4_t*)(smB + (ba ^ 16));
                bf16x8_t bv = cvt8f(bl, bh);
                __builtin_amdgcn_s_setprio(1);
                acc[0][ns] = __builtin_amdgcn_mfma_f32_16x16x32_bf16(af0, bv, acc[0][ns], 0, 0, 0);
                acc[1][ns] = __builtin_amdgcn_mfma_f32_16x16x32_bf16(af1, bv, acc[1][ns], 0, 0, 0);
                __builtin_amdgcn_s_setprio(0);
            }
        }

        if (kt < NKT - 1) {
            // all my ds_reads retired before anyone's DMA may overwrite
            __builtin_amdgcn_sched_barrier(0);
            asm volatile("s_waitcnt lgkmcnt(0)" ::: "memory");
            __builtin_amdgcn_sched_barrier(0);
            __builtin_amdgcn_s_barrier();
            __builtin_amdgcn_sched_barrier(0);
            // DMA tile kt+1 (source advances kt*256 B; LDS dest fixed)
            const int fo = (kt + 1) * BK;
            #pragma unroll
            for (int q = 0; q < 4; ++q) {
                GLOAD16(aSrc[q] + fo, smB + dstByte[q]);
                GLOAD16(bSrc[q] + fo, smB + 32768 + dstByte[q]);
            }
            __builtin_amdgcn_sched_barrier(0);
            asm volatile("s_waitcnt vmcnt(0)" ::: "memory");
            __builtin_amdgcn_sched_barrier(0);
            __builtin_amdgcn_s_barrier();
            __builtin_amdgcn_sched_barrier(0);
        }
    }

    // epilogue: out[b,l] += sum over this wave's i-columns of Z[l,i]*t1[l,i]
    // C/D: col(n=i) = ih*64 + ns*16 + nh, row(m=l) = wv*32 + ms*16 + qd*4 + r
    #pragma unroll
    for (int ms = 0; ms < 2; ++ms) {
        #pragma unroll
        for (int r = 0; r < 4; ++r) {
            const int row = wv * 32 + ms * 16 + qd * 4 + r;
            float ps = 0.f;
            #pragma unroll
            for (int ns = 0; ns < 4; ++ns) {
                const float tv = t1p[(size_t)row * ND1 + ns * 16 + nh];
                ps += acc[ms][ns][r] * tv;
            }
            ps += __shfl_xor(ps, 1);
            ps += __shfl_xor(ps, 2);
            ps += __shfl_xor(ps, 4);
            ps += __shfl_xor(ps, 8);
            if (nh == 0) atomicAdd(&out[b * NL + row], ps);
        }
    }
}

extern "C" void kernel_launch(void* const* d_in, const int* in_sizes, int n_in,
                              void* d_out, int out_size, void* d_ws, size_t ws_size,
                              hipStream_t stream)
{
    const float* t1  = (const float*)d_in[0];
    const float* t2  = (const float*)d_in[1];
    const int* pidx  = (const int*)d_in[2];
    const float* wgt = (const float*)d_in[3];
    float* out = (float*)d_out;

    const int zero_blocks = (out_size + 255) / 256;
    const bool have_ws = ws_size >= NB * sizeof(int);
    int* perm = have_ws ? (int*)d_ws : nullptr;

    pre_kernel<<<dim3(zero_blocks), dim3(256), 0, stream>>>(pidx, perm, out, out_size, have_ws ? 1 : 0);

    if (have_ws)
        pdot_kernel<true><<<dim3(NB * (ND1 / BI)), dim3(512), 0, stream>>>(t1, t2, pidx, wgt, perm, out);
    else
        pdot_kernel<false><<<dim3(NB * (ND1 / BI)), dim3(512), 0, stream>>>(t1, t2, pidx, wgt, nullptr, out);
}